// Round 6
// baseline (273.288 us; speedup 1.0000x reference)
//
#include <hip/hip_runtime.h>
#include <hip/hip_bf16.h>
#include <math.h>

#define B_ 2
#define D_ 256
#define N_ 8192
#define CI_ 128
#define M_ 4096
#define BN_EPS_ 1e-5f

// ---- workspace layout (float offsets) ----
#define OFF_WALL 0                          // bf16 wall[384][256] + wall2[256][128]
#define OFF_THT  65536                      // theta bf16 [B][N][CI]
#define OFF_PHT  (OFF_THT + 1048576)        // phi   bf16 [B][M][CI]
#define OFF_GT   (OFF_PHT + 524288)         // g     bf16 [B][CI][M]
#define OFF_YP   (OFF_GT  + 524288)         // y partial bf16 [4][B][CI][N]
#define OFF_ML   (OFF_YP  + 4194304)        // m/l fp32 [4][B][2][N]
#define OFF_MEAN (OFF_ML + 131072)
#define OFF_RSTD (OFF_MEAN + 256)

typedef __attribute__((ext_vector_type(8))) short bfrag;    // 8 bf16 = 4 VGPRs
typedef __attribute__((ext_vector_type(4))) float f4v;      // 16x16 accumulator
typedef __attribute__((ext_vector_type(16))) float f16v;    // 32x32 accumulator
typedef __attribute__((ext_vector_type(4))) short s4v;      // 4 bf16

__device__ inline unsigned short bf16rne(float x) {
    unsigned u = __float_as_uint(x);
    u += 0x7fff + ((u >> 16) & 1);
    return (unsigned short)(u >> 16);
}

// ---------------- pack weights to bf16: wall[384][256] (g|theta|phi), wall2[256][128] (W) ----
__global__ __launch_bounds__(256) void wconv_kernel(
    const float* __restrict__ gw, const float* __restrict__ tw, const float* __restrict__ pw,
    const float* __restrict__ Ww, short* __restrict__ wall)
{
    int idx = blockIdx.x * 256 + threadIdx.x;      // 0 .. 131071
    int which = idx >> 15;
    int rem = idx & 32767;
    const float* src = (which == 0) ? gw : (which == 1) ? tw : (which == 2) ? pw : Ww;
    wall[idx] = (short)bf16rne(src[rem]);
}

// ---------------- MFMA projections ----------------
// Out[cc][n] = sum_d Wall[cc][d] * f[b][d][n], cc in [0,384): g | theta | phi.
// block 256 = 4 waves; wave owns 96 cc (6 frags) x 32 n (2 frags). grid (N/32, B).
__global__ __launch_bounds__(256, 2) void proj_kernel(
    const float* __restrict__ f, const short* __restrict__ wall,
    const float* __restrict__ tb, const float* __restrict__ gb, const float* __restrict__ pb,
    short* __restrict__ th_t, short* __restrict__ g_t, short* __restrict__ ph_t)
{
    __shared__ short sF[32 * 72];   // f chunk transposed [n][k], stride 72 shorts

    const int tid = threadIdx.x;
    const int wave = tid >> 6, lane = tid & 63;
    const int lq = lane & 15, quad = lane >> 4;
    const int b = blockIdx.y;
    const int n0 = blockIdx.x * 32;

    const float* fb = f + (size_t)b * D_ * N_;

    f4v acc[6][2];
#pragma unroll
    for (int ct = 0; ct < 6; ct++)
#pragma unroll
        for (int nf = 0; nf < 2; nf++) acc[ct][nf] = (f4v){0.f, 0.f, 0.f, 0.f};

    const int sn = tid & 31;     // staging: n within tile
    const int sgrp = tid >> 5;   // staging: d' group of 8

    for (int kc = 0; kc < D_; kc += 64) {
        __syncthreads();
#pragma unroll
        for (int jj = 0; jj < 4; jj++) {
            int dd = kc + sgrp * 8 + 2 * jj;
            float v0 = fb[(size_t)dd * N_ + n0 + sn];
            float v1 = fb[(size_t)(dd + 1) * N_ + n0 + sn];
            unsigned pk = (unsigned)bf16rne(v0) | ((unsigned)bf16rne(v1) << 16);
            *(unsigned*)&sF[sn * 72 + sgrp * 8 + 2 * jj] = pk;
        }
        __syncthreads();

        bfrag afr[6][2], bfr[2][2];
#pragma unroll
        for (int ks = 0; ks < 2; ks++) {
#pragma unroll
            for (int nf = 0; nf < 2; nf++)
                bfr[nf][ks] = *(const bfrag*)&sF[(nf * 16 + lq) * 72 + ks * 32 + quad * 8];
#pragma unroll
            for (int ct = 0; ct < 6; ct++)
                afr[ct][ks] = *(const bfrag*)&wall[(wave * 96 + ct * 16 + lq) * 256 + kc + ks * 32 + quad * 8];
        }
#pragma unroll
        for (int ks = 0; ks < 2; ks++)
#pragma unroll
            for (int ct = 0; ct < 6; ct++) {
                acc[ct][0] = __builtin_amdgcn_mfma_f32_16x16x32_bf16(afr[ct][ks], bfr[0][ks], acc[ct][0], 0, 0, 0);
                acc[ct][1] = __builtin_amdgcn_mfma_f32_16x16x32_bf16(afr[ct][ks], bfr[1][ks], acc[ct][1], 0, 0, 0);
            }
    }

#pragma unroll
    for (int ct = 0; ct < 6; ct++) {
        const int cf = wave * 6 + ct;
#pragma unroll
        for (int nf = 0; nf < 2; nf++) {
            f4v v = acc[ct][nf];
            const int n = n0 + nf * 16 + lq;
            if (cf < 8) {                 // g -> pooled, transposed [c][m]
                const int cb = cf * 16 + quad * 4;
                float pl[4];
#pragma unroll
                for (int r = 0; r < 4; r++) {
                    float o = __shfl_xor(v[r], 1);
                    pl[r] = fmaxf(v[r], o) + gb[cb + r];
                }
                if (!(lq & 1)) {
                    const int m = n >> 1;
#pragma unroll
                    for (int r = 0; r < 4; r++)
                        g_t[((size_t)b * CI_ + cb + r) * M_ + m] = (short)bf16rne(pl[r]);
                }
            } else if (cf < 16) {         // theta [n][c]
                const int cb = (cf - 8) * 16 + quad * 4;
                s4v o;
#pragma unroll
                for (int r = 0; r < 4; r++) o[r] = (short)bf16rne(v[r] + tb[cb + r]);
                *(s4v*)&th_t[((size_t)b * N_ + n) * CI_ + cb] = o;
            } else {                      // phi -> pooled [m][c]
                const int cb = (cf - 16) * 16 + quad * 4;
                float pl[4];
#pragma unroll
                for (int r = 0; r < 4; r++) {
                    float o = __shfl_xor(v[r], 1);
                    pl[r] = fmaxf(v[r], o) + pb[cb + r];
                }
                if (!(lq & 1)) {
                    const int m = n >> 1;
                    s4v o;
#pragma unroll
                    for (int r = 0; r < 4; r++) o[r] = (short)bf16rne(pl[r]);
                    *(s4v*)&ph_t[((size_t)b * M_ + m) * CI_ + cb] = o;
                }
            }
        }
    }
}

// ---------------- MFMA flash attention, 32x32 tiles, key-split 4 ----------------
// block 256 = 4 waves; wave owns 32 q. Q-tile 128, KC=64 keys/chunk, 16 chunks.
// P layout transform in-register: CONSTANT pu[] indices + cndmask on h (no scratch!).
// grid (N/128, B, 4). Writes bf16 unnormalized y^T partials + fp32 (m,l).
__global__ __launch_bounds__(256, 4) void attn_kernel(
    const short* __restrict__ th_p, const short* __restrict__ ph_p,
    const short* __restrict__ g_p, short* __restrict__ yp, float* __restrict__ ml)
{
    __shared__ short sPh[64 * 136];    // phi  [key][ci], 272 B rows (17x16B, odd)
    __shared__ short sG [128 * 72];    // g^T  [c][key],  144 B rows (9x16B, odd)

    const int tid = threadIdx.x;
    const int wave = tid >> 6, lane = tid & 63;
    const int l = lane & 31, h = lane >> 5;
    const int b = blockIdx.y, split = blockIdx.z;
    const int q0 = blockIdx.x * 128;
    const int qg = q0 + wave * 32 + l;

    // theta B-fragments in registers: B[k = 16s + 8h + j][n = q]
    const short* thr = th_p + ((size_t)b * N_ + qg) * CI_;
    bfrag tf[8];
#pragma unroll
    for (int s = 0; s < 8; s++)
        tf[s] = *(const bfrag*)&thr[s * 16 + h * 8];

    f16v yacc[4];
#pragma unroll
    for (int ct = 0; ct < 4; ct++)
#pragma unroll
        for (int r = 0; r < 16; r++) yacc[ct][r] = 0.f;
    float mI = -INFINITY, lI = 0.f;

    const short* phg = ph_p + (size_t)b * M_ * CI_;
    const short* gg  = g_p + (size_t)b * CI_ * M_;

    const int k0 = split * 1024;
    for (int kc = k0; kc < k0 + 1024; kc += 64) {
        __syncthreads();
        // stage phi chunk: 64 rows x 256 B
#pragma unroll
        for (int p = 0; p < 4; p++) {
            int idx = p * 256 + tid;
            int r = idx >> 4, u = idx & 15;
            *(float4*)&sPh[r * 136 + u * 8] = *(const float4*)&phg[(size_t)(kc + r) * 128 + u * 8];
        }
        // stage g^T chunk: 128 rows x 128 B
#pragma unroll
        for (int p = 0; p < 4; p++) {
            int idx = p * 256 + tid;
            int r = idx >> 3, u = idx & 7;
            *(float4*)&sG[r * 72 + u * 8] = *(const float4*)&gg[(size_t)r * M_ + kc + u * 8];
        }
        __syncthreads();

        // S^T = phi . theta : 2 key-tiles of 32; lane holds col q = l, 16 key-rows/tile
        f16v sv[2];
#pragma unroll
        for (int kt = 0; kt < 2; kt++) {
            f16v a;
#pragma unroll
            for (int r = 0; r < 16; r++) a[r] = 0.f;
#pragma unroll
            for (int s = 0; s < 8; s++) {
                bfrag pa = *(const bfrag*)&sPh[(kt * 32 + l) * 136 + s * 16 + h * 8];
                a = __builtin_amdgcn_mfma_f32_32x32x16_bf16(pa, tf[s], a, 0, 0, 0);
            }
            sv[kt] = a;
        }

        // online softmax for q = l (keys split across h halves: one shfl)
        float mx = sv[0][0];
#pragma unroll
        for (int kt = 0; kt < 2; kt++)
#pragma unroll
            for (int r = 0; r < 16; r++) mx = fmaxf(mx, sv[kt][r]);
        mx = fmaxf(mx, __shfl_xor(mx, 32));
        float mnew = fmaxf(mI, mx);
        float al = __expf(mI - mnew);
        float ps = 0.f;
        // pack exp(S) pairs: pu[kt*8 + b2*2 + p] holds keys kt*32 + 8*b2 + 4h + 2p + {0,1}
        unsigned pu[16];
#pragma unroll
        for (int kt = 0; kt < 2; kt++)
#pragma unroll
            for (int i = 0; i < 8; i++) {
                int r = 2 * i;
                float p0 = __expf(sv[kt][r] - mnew);
                float p1 = __expf(sv[kt][r + 1] - mnew);
                ps += p0 + p1;
                pu[kt * 8 + (i >> 1) * 2 + (i & 1)] =
                    (unsigned)bf16rne(p0) | ((unsigned)bf16rne(p1) << 16);
            }
        ps += __shfl_xor(ps, 32);
        lI = lI * al + ps;
        mI = mnew;

        // P -> B-operand frags: pf[s][j] = P[key = 16s + 8h + j][q = l].
        // value with key k: held at half bit2(k), needed at half bit3(k) -> one shfl_xor(32).
        // All pu[] indices are compile-time constants; h only selects VALUES (cndmask).
        bfrag pf[4];
#pragma unroll
        for (int s = 0; s < 4; s++) {
            const int kt = s >> 1;
            const int iA = kt * 8 + ((2 * s) & 3) * 2;       // block used when h==0 as "own"
            const int iB = kt * 8 + ((2 * s + 1) & 3) * 2;   // block used when h==1 as "own"
            unsigned A0 = pu[iA], A1 = pu[iA + 1];
            unsigned B0 = pu[iB], B1 = pu[iB + 1];
            unsigned O0 = h ? B0 : A0;
            unsigned O1 = h ? B1 : A1;
            unsigned Xs0 = h ? A0 : B0;
            unsigned Xs1 = h ? A1 : B1;
            unsigned X0 = (unsigned)__shfl_xor((int)Xs0, 32);
            unsigned X1 = (unsigned)__shfl_xor((int)Xs1, 32);
            union { unsigned u[4]; bfrag v; } t;
            t.u[0] = h ? X0 : O0;
            t.u[1] = h ? X1 : O1;
            t.u[2] = h ? O0 : X0;
            t.u[3] = h ? O1 : X1;
            pf[s] = t.v;
        }

        // rescale accumulators (col q = l matches D-layout col = lane&31)
#pragma unroll
        for (int ct = 0; ct < 4; ct++)
#pragma unroll
            for (int r = 0; r < 16; r++) yacc[ct][r] *= al;

        // PV: y^T += g^T . P
#pragma unroll
        for (int ct = 0; ct < 4; ct++)
#pragma unroll
            for (int s = 0; s < 4; s++) {
                bfrag ga = *(const bfrag*)&sG[(ct * 32 + l) * 72 + s * 16 + h * 8];
                yacc[ct] = __builtin_amdgcn_mfma_f32_32x32x16_bf16(ga, pf[s], yacc[ct], 0, 0, 0);
            }
    }

    // epilogue: bf16 unnormalized partials + (m,l)
    short* yb = yp + (((size_t)split * B_ + b) * CI_) * N_;
#pragma unroll
    for (int ct = 0; ct < 4; ct++)
#pragma unroll
        for (int r = 0; r < 16; r++) {
            int c = ct * 32 + (r & 3) + 8 * (r >> 2) + 4 * h;
            yb[(size_t)c * N_ + qg] = (short)bf16rne(yacc[ct][r]);
        }
    if (h == 0) {
        float* mlb = ml + ((split * B_ + b) * 2) * N_;
        mlb[qg] = mI;
        mlb[N_ + qg] = lI;
    }
}

// ---------------- fused merge(4 splits) + Wy MFMA + bias -> d_out ----------------
// out[b][d][n] = Wb[d] + sum_c W[d][c] * y_merged[c][n].
// grid (N/32, B), block 256 = 4 waves; wave w owns d-tiles {2w,2w+1} x 32 n.
__global__ __launch_bounds__(256) void wy_merge_kernel(
    const short* __restrict__ yp, const float* __restrict__ ml,
    const short* __restrict__ wall2, const float* __restrict__ Wb,
    float* __restrict__ out)
{
    const int tid = threadIdx.x;
    const int wave = tid >> 6, lane = tid & 63;
    const int l = lane & 31, h = lane >> 5;
    const int b = blockIdx.y;
    const int n = blockIdx.x * 32 + l;

    // merge coefficients for this lane's n
    float m[4], lv[4];
#pragma unroll
    for (int sp = 0; sp < 4; sp++) {
        const float* mlb = ml + ((sp * B_ + b) * 2) * N_;
        m[sp] = mlb[n];
        lv[sp] = mlb[N_ + n];
    }
    float mmax = fmaxf(fmaxf(m[0], m[1]), fmaxf(m[2], m[3]));
    float e[4], den = 0.f;
#pragma unroll
    for (int sp = 0; sp < 4; sp++) { e[sp] = __expf(m[sp] - mmax); den += lv[sp] * e[sp]; }
    float inv = 1.0f / den;
#pragma unroll
    for (int sp = 0; sp < 4; sp++) e[sp] *= inv;

    // B-fragments: by[s][j] = y_merged[c = 16s + 8h + j][n]  (coalesced ushort loads)
    const unsigned short* ypu = (const unsigned short*)yp;
    bfrag by[8];
#pragma unroll
    for (int s = 0; s < 8; s++) {
#pragma unroll
        for (int j = 0; j < 8; j++) {
            const int c = s * 16 + h * 8 + j;
            float a = 0.f;
#pragma unroll
            for (int sp = 0; sp < 4; sp++) {
                unsigned short v = ypu[(((size_t)sp * B_ + b) * CI_ + c) * N_ + n];
                a = fmaf(e[sp], __uint_as_float((unsigned)v << 16), a);
            }
            by[s][j] = (short)bf16rne(a);
        }
    }

    f16v acc[2];
#pragma unroll
    for (int rt = 0; rt < 2; rt++)
#pragma unroll
        for (int r = 0; r < 16; r++) acc[rt][r] = 0.f;

#pragma unroll
    for (int s = 0; s < 8; s++)
#pragma unroll
        for (int rt = 0; rt < 2; rt++) {
            bfrag aw = *(const bfrag*)&wall2[((wave * 2 + rt) * 32 + l) * 128 + s * 16 + h * 8];
            acc[rt] = __builtin_amdgcn_mfma_f32_32x32x16_bf16(aw, by[s], acc[rt], 0, 0, 0);
        }

#pragma unroll
    for (int rt = 0; rt < 2; rt++)
#pragma unroll
        for (int r = 0; r < 16; r++) {
            const int d = (wave * 2 + rt) * 32 + (r & 3) + 8 * (r >> 2) + 4 * h;
            out[((size_t)b * D_ + d) * N_ + n] = acc[rt][r] + Wb[d];
        }
}

// ---------------- per-channel batch stats over (b, n) ----------------
__global__ __launch_bounds__(256) void stats_kernel(
    const float* __restrict__ wy, float* __restrict__ mean, float* __restrict__ rstd)
{
    __shared__ float ssum[256], ssq[256];
    int d = blockIdx.x;
    int tid = threadIdx.x;
    float s = 0.f, sq = 0.f;
    for (int b = 0; b < B_; b++) {
        const float* p = wy + (size_t)b * D_ * N_ + (size_t)d * N_;
        for (int i = tid; i < N_; i += 256) {
            float v = p[i];
            s += v;
            sq = fmaf(v, v, sq);
        }
    }
    ssum[tid] = s; ssq[tid] = sq;
    __syncthreads();
    for (int st = 128; st > 0; st >>= 1) {
        if (tid < st) { ssum[tid] += ssum[tid + st]; ssq[tid] += ssq[tid + st]; }
        __syncthreads();
    }
    if (tid == 0) {
        float inv = 1.0f / (float)(B_ * N_);
        float mn = ssum[0] * inv;
        float var = ssq[0] * inv - mn * mn;
        mean[d] = mn;
        rstd[d] = rsqrtf(var + BN_EPS_);
    }
}

// ---------------- BN (affine) + residual, in-place on d_out ----------------
__global__ __launch_bounds__(256) void bn_res_kernel(
    float* __restrict__ out, const float* __restrict__ f,
    const float* __restrict__ mean, const float* __restrict__ rstd,
    const float* __restrict__ gamma, const float* __restrict__ beta)
{
    int i = blockIdx.x * 256 + threadIdx.x;
    size_t e = (size_t)i * 4;
    int d = (int)((e >> 13) & 255);
    float4 wy = ((const float4*)out)[i];
    float4 ff = ((const float4*)f)[i];
    float sc = rstd[d] * gamma[d];
    float mn = mean[d];
    float bt = beta[d];
    float4 r;
    r.x = (wy.x - mn) * sc + bt + ff.x;
    r.y = (wy.y - mn) * sc + bt + ff.y;
    r.z = (wy.z - mn) * sc + bt + ff.z;
    r.w = (wy.w - mn) * sc + bt + ff.w;
    ((float4*)out)[i] = r;
}

extern "C" void kernel_launch(void* const* d_in, const int* in_sizes, int n_in,
                              void* d_out, int out_size, void* d_ws, size_t ws_size,
                              hipStream_t stream)
{
    const float* f   = (const float*)d_in[0];
    const float* g_w = (const float*)d_in[1];
    const float* g_b = (const float*)d_in[2];
    const float* t_w = (const float*)d_in[3];
    const float* t_b = (const float*)d_in[4];
    const float* p_w = (const float*)d_in[5];
    const float* p_b = (const float*)d_in[6];
    const float* W_w = (const float*)d_in[7];
    const float* W_b = (const float*)d_in[8];
    const float* gam = (const float*)d_in[9];
    const float* bet = (const float*)d_in[10];
    float* out = (float*)d_out;
    float* ws = (float*)d_ws;

    short* wall  = (short*)(ws + OFF_WALL);
    short* wall2 = wall + 3 * 32768;
    short* th_t = (short*)(ws + OFF_THT);
    short* ph_t = (short*)(ws + OFF_PHT);
    short* g_t  = (short*)(ws + OFF_GT);
    short* ypart = (short*)(ws + OFF_YP);
    float* mlp = ws + OFF_ML;
    float* mnp = ws + OFF_MEAN;
    float* rsp = ws + OFF_RSTD;

    wconv_kernel<<<512, 256, 0, stream>>>(g_w, t_w, p_w, W_w, wall);
    proj_kernel<<<dim3(N_ / 32, B_), 256, 0, stream>>>(f, wall, t_b, g_b, p_b,
                                                       th_t, g_t, ph_t);
    attn_kernel<<<dim3(N_ / 128, B_, 4), 256, 0, stream>>>(th_t, ph_t, g_t, ypart, mlp);
    wy_merge_kernel<<<dim3(N_ / 32, B_), 256, 0, stream>>>(ypart, mlp, wall2, W_b, out);
    stats_kernel<<<D_, 256, 0, stream>>>(out, mnp, rsp);
    bn_res_kernel<<<(B_ * D_ * N_ / 4) / 256, 256, 0, stream>>>(out, f, mnp, rsp, gam, bet);
}

// Round 7
// 213.422 us; speedup vs baseline: 1.2805x; 1.2805x over previous
//
#include <hip/hip_runtime.h>
#include <hip/hip_bf16.h>
#include <math.h>

#define B_ 2
#define D_ 256
#define N_ 8192
#define CI_ 128
#define M_ 4096
#define BN_EPS_ 1e-5f

// ---- workspace layout (float offsets) ----
#define OFF_WALL 0                          // bf16 wall[384][256] + wall2[256][128]
#define OFF_THT  65536                      // theta bf16 [B][N][CI]
#define OFF_PHT  (OFF_THT + 1048576)        // phi   bf16 [B][M][CI]
#define OFF_GT   (OFF_PHT + 524288)         // g     bf16 [B][CI][M]
#define OFF_YP   (OFF_GT  + 524288)         // y partial bf16 [4][B][CI][N]
#define OFF_ML   (OFF_YP  + 4194304)        // m/l fp32 [4][B][2][N]
#define OFF_MEAN (OFF_ML + 131072)
#define OFF_RSTD (OFF_MEAN + 256)

typedef __attribute__((ext_vector_type(8))) short bfrag;    // 8 bf16 = 4 VGPRs
typedef __attribute__((ext_vector_type(4))) float f4v;      // 16x16 accumulator
typedef __attribute__((ext_vector_type(16))) float f16v;    // 32x32 accumulator
typedef __attribute__((ext_vector_type(4))) short s4v;      // 4 bf16

__device__ inline unsigned short bf16rne(float x) {
    unsigned u = __float_as_uint(x);
    u += 0x7fff + ((u >> 16) & 1);
    return (unsigned short)(u >> 16);
}

// ---------------- pack weights to bf16: wall[384][256] (g|theta|phi), wall2[256][128] (W) ----
__global__ __launch_bounds__(256) void wconv_kernel(
    const float* __restrict__ gw, const float* __restrict__ tw, const float* __restrict__ pw,
    const float* __restrict__ Ww, short* __restrict__ wall)
{
    int idx = blockIdx.x * 256 + threadIdx.x;      // 0 .. 131071
    int which = idx >> 15;
    int rem = idx & 32767;
    const float* src = (which == 0) ? gw : (which == 1) ? tw : (which == 2) ? pw : Ww;
    wall[idx] = (short)bf16rne(src[rem]);
}

// ---------------- MFMA projections ----------------
// Out[cc][n] = sum_d Wall[cc][d] * f[b][d][n], cc in [0,384): g | theta | phi.
// block 256 = 4 waves; wave owns 96 cc (6 frags) x 32 n (2 frags). grid (N/32, B).
__global__ __launch_bounds__(256, 2) void proj_kernel(
    const float* __restrict__ f, const short* __restrict__ wall,
    const float* __restrict__ tb, const float* __restrict__ gb, const float* __restrict__ pb,
    short* __restrict__ th_t, short* __restrict__ g_t, short* __restrict__ ph_t)
{
    __shared__ short sF[32 * 72];   // f chunk transposed [n][k], stride 72 shorts

    const int tid = threadIdx.x;
    const int wave = tid >> 6, lane = tid & 63;
    const int lq = lane & 15, quad = lane >> 4;
    const int b = blockIdx.y;
    const int n0 = blockIdx.x * 32;

    const float* fb = f + (size_t)b * D_ * N_;

    f4v acc[6][2];
#pragma unroll
    for (int ct = 0; ct < 6; ct++)
#pragma unroll
        for (int nf = 0; nf < 2; nf++) acc[ct][nf] = (f4v){0.f, 0.f, 0.f, 0.f};

    const int sn = tid & 31;     // staging: n within tile
    const int sgrp = tid >> 5;   // staging: d' group of 8

    for (int kc = 0; kc < D_; kc += 64) {
        __syncthreads();
#pragma unroll
        for (int jj = 0; jj < 4; jj++) {
            int dd = kc + sgrp * 8 + 2 * jj;
            float v0 = fb[(size_t)dd * N_ + n0 + sn];
            float v1 = fb[(size_t)(dd + 1) * N_ + n0 + sn];
            unsigned pk = (unsigned)bf16rne(v0) | ((unsigned)bf16rne(v1) << 16);
            *(unsigned*)&sF[sn * 72 + sgrp * 8 + 2 * jj] = pk;
        }
        __syncthreads();

        bfrag afr[6][2], bfr[2][2];
#pragma unroll
        for (int ks = 0; ks < 2; ks++) {
#pragma unroll
            for (int nf = 0; nf < 2; nf++)
                bfr[nf][ks] = *(const bfrag*)&sF[(nf * 16 + lq) * 72 + ks * 32 + quad * 8];
#pragma unroll
            for (int ct = 0; ct < 6; ct++)
                afr[ct][ks] = *(const bfrag*)&wall[(wave * 96 + ct * 16 + lq) * 256 + kc + ks * 32 + quad * 8];
        }
#pragma unroll
        for (int ks = 0; ks < 2; ks++)
#pragma unroll
            for (int ct = 0; ct < 6; ct++) {
                acc[ct][0] = __builtin_amdgcn_mfma_f32_16x16x32_bf16(afr[ct][ks], bfr[0][ks], acc[ct][0], 0, 0, 0);
                acc[ct][1] = __builtin_amdgcn_mfma_f32_16x16x32_bf16(afr[ct][ks], bfr[1][ks], acc[ct][1], 0, 0, 0);
            }
    }

#pragma unroll
    for (int ct = 0; ct < 6; ct++) {
        const int cf = wave * 6 + ct;
#pragma unroll
        for (int nf = 0; nf < 2; nf++) {
            f4v v = acc[ct][nf];
            const int n = n0 + nf * 16 + lq;
            if (cf < 8) {                 // g -> pooled, transposed [c][m]
                const int cb = cf * 16 + quad * 4;
                float pl[4];
#pragma unroll
                for (int r = 0; r < 4; r++) {
                    float o = __shfl_xor(v[r], 1);
                    pl[r] = fmaxf(v[r], o) + gb[cb + r];
                }
                if (!(lq & 1)) {
                    const int m = n >> 1;
#pragma unroll
                    for (int r = 0; r < 4; r++)
                        g_t[((size_t)b * CI_ + cb + r) * M_ + m] = (short)bf16rne(pl[r]);
                }
            } else if (cf < 16) {         // theta [n][c]
                const int cb = (cf - 8) * 16 + quad * 4;
                s4v o;
#pragma unroll
                for (int r = 0; r < 4; r++) o[r] = (short)bf16rne(v[r] + tb[cb + r]);
                *(s4v*)&th_t[((size_t)b * N_ + n) * CI_ + cb] = o;
            } else {                      // phi -> pooled [m][c]
                const int cb = (cf - 16) * 16 + quad * 4;
                float pl[4];
#pragma unroll
                for (int r = 0; r < 4; r++) {
                    float o = __shfl_xor(v[r], 1);
                    pl[r] = fmaxf(v[r], o) + pb[cb + r];
                }
                if (!(lq & 1)) {
                    const int m = n >> 1;
                    s4v o;
#pragma unroll
                    for (int r = 0; r < 4; r++) o[r] = (short)bf16rne(pl[r]);
                    *(s4v*)&ph_t[((size_t)b * M_ + m) * CI_ + cb] = o;
                }
            }
        }
    }
}

// ---------------- MFMA flash attention, 32x32 tiles, key-split 4 ----------------
// block 256 = 4 waves; wave owns 32 q. Q-tile 128, KC=64 keys/chunk, 16 chunks.
// P layout transform in-register: CONSTANT pu[] indices + cndmask on h.
// __launch_bounds__(256,3): 170 reg/wave budget — this loop needs ~164 (84 VGPR +
// 80 acc measured at R5); bound 4 (=128) forces heavy scratch spill (R6: 116 MB writes).
// grid (N/128, B, 4). Writes bf16 unnormalized y^T partials + fp32 (m,l).
__global__ __launch_bounds__(256, 3) void attn_kernel(
    const short* __restrict__ th_p, const short* __restrict__ ph_p,
    const short* __restrict__ g_p, short* __restrict__ yp, float* __restrict__ ml)
{
    __shared__ short sPh[64 * 136];    // phi  [key][ci], 272 B rows (17x16B, odd)
    __shared__ short sG [128 * 72];    // g^T  [c][key],  144 B rows (9x16B, odd)

    const int tid = threadIdx.x;
    const int wave = tid >> 6, lane = tid & 63;
    const int l = lane & 31, h = lane >> 5;
    const int b = blockIdx.y, split = blockIdx.z;
    const int q0 = blockIdx.x * 128;
    const int qg = q0 + wave * 32 + l;

    // theta B-fragments in registers: B[k = 16s + 8h + j][n = q]
    const short* thr = th_p + ((size_t)b * N_ + qg) * CI_;
    bfrag tf[8];
#pragma unroll
    for (int s = 0; s < 8; s++)
        tf[s] = *(const bfrag*)&thr[s * 16 + h * 8];

    f16v yacc[4];
#pragma unroll
    for (int ct = 0; ct < 4; ct++)
#pragma unroll
        for (int r = 0; r < 16; r++) yacc[ct][r] = 0.f;
    float mI = -INFINITY, lI = 0.f;

    const short* phg = ph_p + (size_t)b * M_ * CI_;
    const short* gg  = g_p + (size_t)b * CI_ * M_;

    const int k0 = split * 1024;
    for (int kc = k0; kc < k0 + 1024; kc += 64) {
        __syncthreads();
        // stage phi chunk: 64 rows x 256 B
#pragma unroll
        for (int p = 0; p < 4; p++) {
            int idx = p * 256 + tid;
            int r = idx >> 4, u = idx & 15;
            *(float4*)&sPh[r * 136 + u * 8] = *(const float4*)&phg[(size_t)(kc + r) * 128 + u * 8];
        }
        // stage g^T chunk: 128 rows x 128 B
#pragma unroll
        for (int p = 0; p < 4; p++) {
            int idx = p * 256 + tid;
            int r = idx >> 3, u = idx & 7;
            *(float4*)&sG[r * 72 + u * 8] = *(const float4*)&gg[(size_t)r * M_ + kc + u * 8];
        }
        __syncthreads();

        // S^T = phi . theta : 2 key-tiles of 32; lane holds col q = l, 16 key-rows/tile
        f16v sv[2];
#pragma unroll
        for (int kt = 0; kt < 2; kt++) {
            f16v a;
#pragma unroll
            for (int r = 0; r < 16; r++) a[r] = 0.f;
#pragma unroll
            for (int s = 0; s < 8; s++) {
                bfrag pa = *(const bfrag*)&sPh[(kt * 32 + l) * 136 + s * 16 + h * 8];
                a = __builtin_amdgcn_mfma_f32_32x32x16_bf16(pa, tf[s], a, 0, 0, 0);
            }
            sv[kt] = a;
        }

        // online softmax for q = l (keys split across h halves: one shfl)
        float mx = sv[0][0];
#pragma unroll
        for (int kt = 0; kt < 2; kt++)
#pragma unroll
            for (int r = 0; r < 16; r++) mx = fmaxf(mx, sv[kt][r]);
        mx = fmaxf(mx, __shfl_xor(mx, 32));
        float mnew = fmaxf(mI, mx);
        float al = __expf(mI - mnew);
        float ps = 0.f;
        // pack exp(S) pairs: pu[kt*8 + b2*2 + p] holds keys kt*32 + 8*b2 + 4h + 2p + {0,1}
        unsigned pu[16];
#pragma unroll
        for (int kt = 0; kt < 2; kt++)
#pragma unroll
            for (int i = 0; i < 8; i++) {
                int r = 2 * i;
                float p0 = __expf(sv[kt][r] - mnew);
                float p1 = __expf(sv[kt][r + 1] - mnew);
                ps += p0 + p1;
                pu[kt * 8 + (i >> 1) * 2 + (i & 1)] =
                    (unsigned)bf16rne(p0) | ((unsigned)bf16rne(p1) << 16);
            }
        ps += __shfl_xor(ps, 32);
        lI = lI * al + ps;
        mI = mnew;

        // P -> B-operand frags: pf[s][j] = P[key = 16s + 8h + j][q = l].
        // value with key k: held at half bit2(k), needed at half bit3(k) -> one shfl_xor(32).
        // All pu[] indices are compile-time constants; h only selects VALUES (cndmask).
        bfrag pf[4];
#pragma unroll
        for (int s = 0; s < 4; s++) {
            const int kt = s >> 1;
            const int iA = kt * 8 + ((2 * s) & 3) * 2;       // block used when h==0 as "own"
            const int iB = kt * 8 + ((2 * s + 1) & 3) * 2;   // block used when h==1 as "own"
            unsigned A0 = pu[iA], A1 = pu[iA + 1];
            unsigned B0 = pu[iB], B1 = pu[iB + 1];
            unsigned O0 = h ? B0 : A0;
            unsigned O1 = h ? B1 : A1;
            unsigned Xs0 = h ? A0 : B0;
            unsigned Xs1 = h ? A1 : B1;
            unsigned X0 = (unsigned)__shfl_xor((int)Xs0, 32);
            unsigned X1 = (unsigned)__shfl_xor((int)Xs1, 32);
            union { unsigned u[4]; bfrag v; } t;
            t.u[0] = h ? X0 : O0;
            t.u[1] = h ? X1 : O1;
            t.u[2] = h ? O0 : X0;
            t.u[3] = h ? O1 : X1;
            pf[s] = t.v;
        }

        // rescale accumulators (col q = l matches D-layout col = lane&31)
#pragma unroll
        for (int ct = 0; ct < 4; ct++)
#pragma unroll
            for (int r = 0; r < 16; r++) yacc[ct][r] *= al;

        // PV: y^T += g^T . P
#pragma unroll
        for (int ct = 0; ct < 4; ct++)
#pragma unroll
            for (int s = 0; s < 4; s++) {
                bfrag ga = *(const bfrag*)&sG[(ct * 32 + l) * 72 + s * 16 + h * 8];
                yacc[ct] = __builtin_amdgcn_mfma_f32_32x32x16_bf16(ga, pf[s], yacc[ct], 0, 0, 0);
            }
    }

    // epilogue: bf16 unnormalized partials + (m,l)
    short* yb = yp + (((size_t)split * B_ + b) * CI_) * N_;
#pragma unroll
    for (int ct = 0; ct < 4; ct++)
#pragma unroll
        for (int r = 0; r < 16; r++) {
            int c = ct * 32 + (r & 3) + 8 * (r >> 2) + 4 * h;
            yb[(size_t)c * N_ + qg] = (short)bf16rne(yacc[ct][r]);
        }
    if (h == 0) {
        float* mlb = ml + ((split * B_ + b) * 2) * N_;
        mlb[qg] = mI;
        mlb[N_ + qg] = lI;
    }
}

// ---------------- fused merge(4 splits) + Wy MFMA + bias -> d_out ----------------
// out[b][d][n] = Wb[d] + sum_c W[d][c] * y_merged[c][n].
// grid (N/32, B), block 256 = 4 waves; wave w owns d-tiles {2w,2w+1} x 32 n.
__global__ __launch_bounds__(256) void wy_merge_kernel(
    const short* __restrict__ yp, const float* __restrict__ ml,
    const short* __restrict__ wall2, const float* __restrict__ Wb,
    float* __restrict__ out)
{
    const int tid = threadIdx.x;
    const int wave = tid >> 6, lane = tid & 63;
    const int l = lane & 31, h = lane >> 5;
    const int b = blockIdx.y;
    const int n = blockIdx.x * 32 + l;

    // merge coefficients for this lane's n
    float m[4], lv[4];
#pragma unroll
    for (int sp = 0; sp < 4; sp++) {
        const float* mlb = ml + ((sp * B_ + b) * 2) * N_;
        m[sp] = mlb[n];
        lv[sp] = mlb[N_ + n];
    }
    float mmax = fmaxf(fmaxf(m[0], m[1]), fmaxf(m[2], m[3]));
    float e[4], den = 0.f;
#pragma unroll
    for (int sp = 0; sp < 4; sp++) { e[sp] = __expf(m[sp] - mmax); den += lv[sp] * e[sp]; }
    float inv = 1.0f / den;
#pragma unroll
    for (int sp = 0; sp < 4; sp++) e[sp] *= inv;

    // B-fragments: by[s][j] = y_merged[c = 16s + 8h + j][n]  (coalesced ushort loads)
    const unsigned short* ypu = (const unsigned short*)yp;
    bfrag by[8];
#pragma unroll
    for (int s = 0; s < 8; s++) {
#pragma unroll
        for (int j = 0; j < 8; j++) {
            const int c = s * 16 + h * 8 + j;
            float a = 0.f;
#pragma unroll
            for (int sp = 0; sp < 4; sp++) {
                unsigned short v = ypu[(((size_t)sp * B_ + b) * CI_ + c) * N_ + n];
                a = fmaf(e[sp], __uint_as_float((unsigned)v << 16), a);
            }
            by[s][j] = (short)bf16rne(a);
        }
    }

    f16v acc[2];
#pragma unroll
    for (int rt = 0; rt < 2; rt++)
#pragma unroll
        for (int r = 0; r < 16; r++) acc[rt][r] = 0.f;

#pragma unroll
    for (int s = 0; s < 8; s++)
#pragma unroll
        for (int rt = 0; rt < 2; rt++) {
            bfrag aw = *(const bfrag*)&wall2[((wave * 2 + rt) * 32 + l) * 128 + s * 16 + h * 8];
            acc[rt] = __builtin_amdgcn_mfma_f32_32x32x16_bf16(aw, by[s], acc[rt], 0, 0, 0);
        }

#pragma unroll
    for (int rt = 0; rt < 2; rt++)
#pragma unroll
        for (int r = 0; r < 16; r++) {
            const int d = (wave * 2 + rt) * 32 + (r & 3) + 8 * (r >> 2) + 4 * h;
            out[((size_t)b * D_ + d) * N_ + n] = acc[rt][r] + Wb[d];
        }
}

// ---------------- per-channel batch stats over (b, n) ----------------
__global__ __launch_bounds__(256) void stats_kernel(
    const float* __restrict__ wy, float* __restrict__ mean, float* __restrict__ rstd)
{
    __shared__ float ssum[256], ssq[256];
    int d = blockIdx.x;
    int tid = threadIdx.x;
    float s = 0.f, sq = 0.f;
    for (int b = 0; b < B_; b++) {
        const float* p = wy + (size_t)b * D_ * N_ + (size_t)d * N_;
        for (int i = tid; i < N_; i += 256) {
            float v = p[i];
            s += v;
            sq = fmaf(v, v, sq);
        }
    }
    ssum[tid] = s; ssq[tid] = sq;
    __syncthreads();
    for (int st = 128; st > 0; st >>= 1) {
        if (tid < st) { ssum[tid] += ssum[tid + st]; ssq[tid] += ssq[tid + st]; }
        __syncthreads();
    }
    if (tid == 0) {
        float inv = 1.0f / (float)(B_ * N_);
        float mn = ssum[0] * inv;
        float var = ssq[0] * inv - mn * mn;
        mean[d] = mn;
        rstd[d] = rsqrtf(var + BN_EPS_);
    }
}

// ---------------- BN (affine) + residual, in-place on d_out ----------------
__global__ __launch_bounds__(256) void bn_res_kernel(
    float* __restrict__ out, const float* __restrict__ f,
    const float* __restrict__ mean, const float* __restrict__ rstd,
    const float* __restrict__ gamma, const float* __restrict__ beta)
{
    int i = blockIdx.x * 256 + threadIdx.x;
    size_t e = (size_t)i * 4;
    int d = (int)((e >> 13) & 255);
    float4 wy = ((const float4*)out)[i];
    float4 ff = ((const float4*)f)[i];
    float sc = rstd[d] * gamma[d];
    float mn = mean[d];
    float bt = beta[d];
    float4 r;
    r.x = (wy.x - mn) * sc + bt + ff.x;
    r.y = (wy.y - mn) * sc + bt + ff.y;
    r.z = (wy.z - mn) * sc + bt + ff.z;
    r.w = (wy.w - mn) * sc + bt + ff.w;
    ((float4*)out)[i] = r;
}

extern "C" void kernel_launch(void* const* d_in, const int* in_sizes, int n_in,
                              void* d_out, int out_size, void* d_ws, size_t ws_size,
                              hipStream_t stream)
{
    const float* f   = (const float*)d_in[0];
    const float* g_w = (const float*)d_in[1];
    const float* g_b = (const float*)d_in[2];
    const float* t_w = (const float*)d_in[3];
    const float* t_b = (const float*)d_in[4];
    const float* p_w = (const float*)d_in[5];
    const float* p_b = (const float*)d_in[6];
    const float* W_w = (const float*)d_in[7];
    const float* W_b = (const float*)d_in[8];
    const float* gam = (const float*)d_in[9];
    const float* bet = (const float*)d_in[10];
    float* out = (float*)d_out;
    float* ws = (float*)d_ws;

    short* wall  = (short*)(ws + OFF_WALL);
    short* wall2 = wall + 3 * 32768;
    short* th_t = (short*)(ws + OFF_THT);
    short* ph_t = (short*)(ws + OFF_PHT);
    short* g_t  = (short*)(ws + OFF_GT);
    short* ypart = (short*)(ws + OFF_YP);
    float* mlp = ws + OFF_ML;
    float* mnp = ws + OFF_MEAN;
    float* rsp = ws + OFF_RSTD;

    wconv_kernel<<<512, 256, 0, stream>>>(g_w, t_w, p_w, W_w, wall);
    proj_kernel<<<dim3(N_ / 32, B_), 256, 0, stream>>>(f, wall, t_b, g_b, p_b,
                                                       th_t, g_t, ph_t);
    attn_kernel<<<dim3(N_ / 128, B_, 4), 256, 0, stream>>>(th_t, ph_t, g_t, ypart, mlp);
    wy_merge_kernel<<<dim3(N_ / 32, B_), 256, 0, stream>>>(ypart, mlp, wall2, W_b, out);
    stats_kernel<<<D_, 256, 0, stream>>>(out, mnp, rsp);
    bn_res_kernel<<<(B_ * D_ * N_ / 4) / 256, 256, 0, stream>>>(out, f, mnp, rsp, gam, bet);
}